// Round 6
// baseline (435.039 us; speedup 1.0000x reference)
//
#include <hip/hip_runtime.h>
#include <math.h>

#define NK 512
#define DD 256
#define NB 32
#define NT 4096

typedef __attribute__((ext_vector_type(8))) _Float16 f16x8;
typedef __attribute__((ext_vector_type(4))) float f32x4;

#define MARGIN 1.5e-4f
#define DCH 16      // d per chunk
#define NCH 16      // chunks (DD/DCH)
#define APAD 40     // shorts per LDS row (80 B: period-8 bank rotation, 2-way = free)
#define ASZ (128 * APAD)
#define BSZ (256 * APAD)

__device__ __forceinline__ unsigned short f16bits(float x) {
    _Float16 h = (_Float16)x;           // v_cvt_f16_f32, RNE
    unsigned short s;
    __builtin_memcpy(&s, &h, 2);
    return s;
}

// ---------------------------------------------------------------------------
// Prep: blocks 0..15 build Wpp (f16 w*4096, duplicated per-d slot pair);
// block 16 computes wsq (fp64 -> fp32 once).
// Wpp layout: [(c*512 + k)*32] shorts, c = d-chunk, k = code.
// ---------------------------------------------------------------------------
__global__ __launch_bounds__(512) void prep_kernel(const float* __restrict__ W,
                                                   unsigned short* __restrict__ Wpp,
                                                   float* __restrict__ wsq,
                                                   int* __restrict__ cnt) {
    const int bx = blockIdx.x;
    const int k  = threadIdx.x;   // 0..511
    if (bx == 0 && k == 0) *cnt = 0;
    if (bx < NCH) {
        const int d0 = bx * DCH;
        float w[16];
        const float4* src4 = (const float4*)(W + (size_t)k * DD + d0);
        #pragma unroll
        for (int q = 0; q < 4; ++q) {
            float4 v = src4[q];
            w[4 * q + 0] = v.x; w[4 * q + 1] = v.y; w[4 * q + 2] = v.z; w[4 * q + 3] = v.w;
        }
        __align__(16) unsigned int dw[16];
        #pragma unroll
        for (int j = 0; j < 16; ++j) {
            unsigned short s = f16bits(w[j] * 4096.0f);  // exact pow2 scale, then RNE
            dw[j] = (unsigned int)s | ((unsigned int)s << 16);  // (wh, wh) slot pair
        }
        unsigned short* dst = Wpp + ((size_t)bx * 512 + k) * 32;
        #pragma unroll
        for (int j = 0; j < 4; ++j) ((int4*)dst)[j] = ((const int4*)dw)[j];
    } else {
        const float4* row = (const float4*)(W + (size_t)k * DD);
        double s = 0.0;
        #pragma unroll 8
        for (int i = 0; i < DD / 4; ++i) {
            float4 v = row[i];
            s += (double)v.x * v.x + (double)v.y * v.y + (double)v.z * v.z + (double)v.w * v.w;
        }
        wsq[k] = (float)s;
    }
}

// ---------------------------------------------------------------------------
// Phase 1: block = 128 t x 256 codes (h = bx&1). 256 thr, 4 waves of 64x128.
// K' = 512 (f16 2-slot z, 1-slot w scaled 2^12), 16 chunks of 32 slots.
// LDS double-buffered: next chunk's global loads issue before current MFMA.
// Emits per (t,h): (q1, q2, i1) after the reference fp32 rounding chain.
// ---------------------------------------------------------------------------
__global__ __launch_bounds__(256, 2) void vq_phase1(const float* __restrict__ Z,
                                                    const unsigned short* __restrict__ Wpp,
                                                    const float* __restrict__ wsq,
                                                    float* __restrict__ gq1,
                                                    float* __restrict__ gq2,
                                                    int* __restrict__ gi1) {
    __shared__ __align__(16) short As[2 * ASZ];  // 20480 B
    __shared__ __align__(16) short Bs[2 * BSZ];  // 40960 B  (total 60 KB)

    const int tid  = threadIdx.x;
    const int wave = tid >> 6;
    const int lane = tid & 63;
    const int lm   = lane & 15;
    const int lq   = lane >> 4;
    const int mw   = wave & 1;   // t half
    const int nw   = wave >> 1;  // k half of the 256

    const int bx = blockIdx.x;
    const int h  = bx & 1;
    const int tl = bx >> 1;
    const int b  = tl >> 5;
    const int t0 = (tl & 31) * 128;

    const int t_l = tid & 127;
    const int dg  = tid >> 7;    // 0..1, 8 d each per chunk

    const float* zcol = Z + (size_t)b * DD * NT + t0 + t_l;
    const unsigned short* wrow = Wpp + (size_t)(h * 256 + tid) * 32;

    f32x4 acc[4][8];
    #pragma unroll
    for (int mt = 0; mt < 4; ++mt)
        #pragma unroll
        for (int nt = 0; nt < 8; ++nt)
            acc[mt][nt] = (f32x4){0.f, 0.f, 0.f, 0.f};

    double zacc = 0.0;

    // ---- prologue: stage chunk 0 into buffer 0
    {
        float zv[8];
        #pragma unroll
        for (int j = 0; j < 8; ++j)
            zv[j] = zcol[(size_t)(dg * 8 + j) * NT];
        #pragma unroll
        for (int j = 0; j < 8; ++j)
            zacc = fma((double)zv[j], (double)zv[j], zacc);
        __align__(16) unsigned int u[8];
        #pragma unroll
        for (int j = 0; j < 8; ++j) {
            _Float16 zh = (_Float16)zv[j];
            float rz = zv[j] - (float)zh;
            unsigned short hs, ls;
            __builtin_memcpy(&hs, &zh, 2);
            ls = f16bits(rz);
            u[j] = (unsigned int)hs | ((unsigned int)ls << 16);
        }
        int4* dst = (int4*)&As[t_l * APAD + dg * 16];
        dst[0] = ((const int4*)u)[0];
        dst[1] = ((const int4*)u)[1];

        const int4* src = (const int4*)wrow;   // chunk 0
        int4* bd = (int4*)&Bs[tid * APAD];
        bd[0] = src[0]; bd[1] = src[1]; bd[2] = src[2]; bd[3] = src[3];
    }

    for (int c = 0; c < NCH; ++c) {
        const int cur = c & 1;
        const int nxt = cur ^ 1;
        __syncthreads();   // buf[cur] writes visible; buf[nxt] readers done

        // ---- issue next chunk's global loads FIRST (latency hidden by MFMA)
        float zv[8];
        int4 bv[4];
        if (c + 1 < NCH) {
            const int d0n = (c + 1) * DCH;
            #pragma unroll
            for (int j = 0; j < 8; ++j)
                zv[j] = zcol[(size_t)(d0n + dg * 8 + j) * NT];
            const int4* src = (const int4*)(wrow + (size_t)(c + 1) * 512 * 32);
            bv[0] = src[0]; bv[1] = src[1]; bv[2] = src[2]; bv[3] = src[3];
        }

        // ---- MFMA on buf[cur]
        {
            f16x8 a[4], bb[8];
            #pragma unroll
            for (int mt = 0; mt < 4; ++mt)
                a[mt] = *(const f16x8*)&As[cur * ASZ + (mw * 64 + mt * 16 + lm) * APAD + lq * 8];
            #pragma unroll
            for (int nt = 0; nt < 8; ++nt)
                bb[nt] = *(const f16x8*)&Bs[cur * BSZ + (nw * 128 + nt * 16 + lm) * APAD + lq * 8];
            #pragma unroll
            for (int mt = 0; mt < 4; ++mt)
                #pragma unroll
                for (int nt = 0; nt < 8; ++nt)
                    acc[mt][nt] = __builtin_amdgcn_mfma_f32_16x16x32_f16(
                        a[mt], bb[nt], acc[mt][nt], 0, 0, 0);
        }

        // ---- split + stage next chunk into buf[nxt]
        if (c + 1 < NCH) {
            #pragma unroll
            for (int j = 0; j < 8; ++j)
                zacc = fma((double)zv[j], (double)zv[j], zacc);
            __align__(16) unsigned int u[8];
            #pragma unroll
            for (int j = 0; j < 8; ++j) {
                _Float16 zh = (_Float16)zv[j];
                float rz = zv[j] - (float)zh;
                unsigned short hs, ls;
                __builtin_memcpy(&hs, &zh, 2);
                ls = f16bits(rz);
                u[j] = (unsigned int)hs | ((unsigned int)ls << 16);
            }
            int4* dst = (int4*)&As[nxt * ASZ + t_l * APAD + dg * 16];
            dst[0] = ((const int4*)u)[0];
            dst[1] = ((const int4*)u)[1];
            int4* bd = (int4*)&Bs[nxt * BSZ + tid * APAD];
            bd[0] = bv[0]; bd[1] = bv[1]; bd[2] = bv[2]; bd[3] = bv[3];
        }
    }

    // ---- epilogue: zsq reduce (fp64 -> fp32 once), chain, per-t top-2
    __syncthreads();
    double* zred = (double*)As;
    zred[dg * 128 + t_l] = zacc;
    __syncthreads();
    float* zf = (float*)Bs;
    if (tid < 128) zf[tid] = (float)(zred[tid] + zred[128 + tid]);
    __syncthreads();

    float wq[8];
    #pragma unroll
    for (int nt = 0; nt < 8; ++nt)
        wq[nt] = wsq[h * 256 + nw * 128 + nt * 16 + lm];
    const int kbase = h * 256 + nw * 128 + lm;

    float* cb1 = (float*)As;          // [128][2]
    float* cb2 = cb1 + 256;
    int*   cbi = (int*)(cb2 + 256);

    #pragma unroll
    for (int mt = 0; mt < 4; ++mt) {
        #pragma unroll
        for (int r = 0; r < 4; ++r) {
            float zz = zf[mw * 64 + mt * 16 + lq * 4 + r];
            float q1 = INFINITY, q2 = INFINITY;
            int i1 = 0x7fffffff;
            #pragma unroll
            for (int nt = 0; nt < 8; ++nt) {
                // acc holds cross*2^12; fl(2*cross) = acc * 2^-11 (exact pow2)
                float c2   = __fmul_rn(acc[mt][nt][r], 4.8828125e-4f);
                float dist = __fadd_rn(__fsub_rn(zz, c2), wq[nt]);
                int kk = kbase + nt * 16;
                if (dist < q1 || (dist == q1 && kk < i1)) { q2 = q1; q1 = dist; i1 = kk; }
                else if (dist < q2) q2 = dist;
            }
            #pragma unroll
            for (int mk = 1; mk <= 8; mk <<= 1) {
                float o1 = __shfl_xor(q1, mk);
                float o2 = __shfl_xor(q2, mk);
                int   oi = __shfl_xor(i1, mk);
                if (o1 < q1 || (o1 == q1 && oi < i1)) { q2 = fminf(q1, o2); q1 = o1; i1 = oi; }
                else { q2 = fminf(o1, q2); }
            }
            if (lm == 0) {
                int m = mw * 64 + mt * 16 + lq * 4 + r;
                cb1[m * 2 + nw] = q1;
                cb2[m * 2 + nw] = q2;
                cbi[m * 2 + nw] = i1;
            }
        }
    }
    __syncthreads();
    if (tid < 128) {
        float a1 = cb1[tid * 2],     a2 = cb2[tid * 2];     int ai = cbi[tid * 2];
        float b1 = cb1[tid * 2 + 1], b2 = cb2[tid * 2 + 1]; int bi = cbi[tid * 2 + 1];
        float q1, q2; int i1;
        if (b1 < a1 || (b1 == a1 && bi < ai)) { q1 = b1; i1 = bi; q2 = fminf(a1, b2); }
        else { q1 = a1; i1 = ai; q2 = fminf(b1, a2); }
        size_t bt = (size_t)b * NT + t0 + tid;
        gq1[bt * 2 + h] = q1;
        gq2[bt * 2 + h] = q2;
        gi1[bt * 2 + h] = i1;
    }
}

// ---------------------------------------------------------------------------
// Merge: combine halves, write approx argmin, compact near-ties globally.
// ---------------------------------------------------------------------------
__global__ __launch_bounds__(256) void vq_merge(const float* __restrict__ gq1,
                                                const float* __restrict__ gq2,
                                                const int* __restrict__ gi1,
                                                int* __restrict__ out,
                                                int* __restrict__ list,
                                                int* __restrict__ cnt) {
    const int bt = blockIdx.x * 256 + threadIdx.x;
    float a1 = gq1[(size_t)bt * 2],     a2 = gq2[(size_t)bt * 2];     int ai = gi1[(size_t)bt * 2];
    float b1 = gq1[(size_t)bt * 2 + 1], b2 = gq2[(size_t)bt * 2 + 1]; int bi = gi1[(size_t)bt * 2 + 1];
    float q1, q2; int i1;
    if (b1 < a1 || (b1 == a1 && bi < ai)) { q1 = b1; i1 = bi; q2 = fminf(a1, b2); }
    else { q1 = a1; i1 = ai; q2 = fminf(b1, a2); }
    out[bt] = i1;
    if (q2 - q1 <= MARGIN) {
        int idx = atomicAdd(cnt, 1);
        list[idx] = bt;
    }
}

// ---------------------------------------------------------------------------
// Fix: ONE BLOCK PER FLAGGED ITEM (grid-stride). 256 threads: one z element
// per thread (single latency round), 2 codes per thread, exact fp32 chain
// (ascending-d fmaf, fp64 zsq rounded once) -- identical to validated path.
// ---------------------------------------------------------------------------
__global__ __launch_bounds__(256) void vq_fix(const float* __restrict__ Z,
                                              const float* __restrict__ W,
                                              const float* __restrict__ wsq,
                                              const int* __restrict__ list,
                                              const int* __restrict__ cnt,
                                              int* __restrict__ out) {
    __shared__ __align__(16) float Zs[256];
    __shared__ double pz[32];
    __shared__ float zsq_s;
    __shared__ float rv[4];
    __shared__ int   ri[4];

    const int tid  = threadIdx.x;
    const int lane = tid & 63;
    const int wv   = tid >> 6;
    const int n    = *cnt;

    for (int it = blockIdx.x; it < n; it += gridDim.x) {
        __syncthreads();
        const int bt = list[it];
        const int bb = bt >> 12, t = bt & 4095;
        Zs[tid] = Z[(size_t)bb * DD * NT + (size_t)tid * NT + t];
        __syncthreads();

        if (tid < 32) {
            double s = 0.0;
            #pragma unroll
            for (int j = 0; j < 8; ++j) {
                double zz = (double)Zs[tid * 8 + j];
                s = fma(zz, zz, s);
            }
            pz[tid] = s;
        }
        __syncthreads();
        if (tid == 0) {
            double s = 0.0;
            #pragma unroll
            for (int j = 0; j < 32; ++j) s += pz[j];
            zsq_s = (float)s;
        }
        __syncthreads();

        // two codes per thread: k = tid, tid+256; ascending-d fmaf chains
        const float4* w0 = (const float4*)(W + (size_t)tid * DD);
        const float4* w1 = (const float4*)(W + (size_t)(tid + 256) * DD);
        float a0 = 0.f, a1 = 0.f;
        #pragma unroll 8
        for (int q = 0; q < 64; ++q) {
            float4 x = w0[q];
            float4 y = w1[q];
            float4 z4 = *(const float4*)&Zs[4 * q];   // LDS broadcast
            a0 = fmaf(z4.x, x.x, a0); a0 = fmaf(z4.y, x.y, a0);
            a0 = fmaf(z4.z, x.z, a0); a0 = fmaf(z4.w, x.w, a0);
            a1 = fmaf(z4.x, y.x, a1); a1 = fmaf(z4.y, y.y, a1);
            a1 = fmaf(z4.z, y.z, a1); a1 = fmaf(z4.w, y.w, a1);
        }
        float zsf = zsq_s;
        float d0 = __fadd_rn(__fsub_rn(zsf, __fmul_rn(2.0f, a0)), wsq[tid]);
        float d1 = __fadd_rn(__fsub_rn(zsf, __fmul_rn(2.0f, a1)), wsq[tid + 256]);

        float v = d0; int ix = tid;
        if (d1 < v) { v = d1; ix = tid + 256; }
        #pragma unroll
        for (int mk = 1; mk <= 32; mk <<= 1) {
            float ov = __shfl_xor(v, mk);
            int   oi = __shfl_xor(ix, mk);
            if (ov < v || (ov == v && oi < ix)) { v = ov; ix = oi; }
        }
        if (lane == 0) { rv[wv] = v; ri[wv] = ix; }
        __syncthreads();
        if (tid == 0) {
            float bv = rv[0]; int bi = ri[0];
            #pragma unroll
            for (int w = 1; w < 4; ++w) {
                if (rv[w] < bv || (rv[w] == bv && ri[w] < bi)) { bv = rv[w]; bi = ri[w]; }
            }
            out[bt] = bi;
        }
    }
}

// ---------------------------------------------------------------------------
// Fallback (R1 kernel) if ws is too small.
// ---------------------------------------------------------------------------
#define BT 128
#define BK 128
#define DCHUNK 32
#define NKC (NK / BK)
#define NDC (DD / DCHUNK)
#define WSTR (BK + 4)

__global__ __launch_bounds__(256) void vq_fallback(const float* __restrict__ Z,
                                                   const float* __restrict__ W,
                                                   int* __restrict__ out) {
    __shared__ __align__(16) float Zs[DCHUNK * BT];
    __shared__ __align__(16) float Ws[DCHUNK * WSTR];
    __shared__ float wsqs[NK];

    const int tid = threadIdx.x;
    const int tx  = tid & 15;
    const int ty  = tid >> 4;
    const int b   = blockIdx.y;
    const int t0  = blockIdx.x * BT;

    for (int k = tid; k < NK; k += 256) {
        const float4* row = (const float4*)(W + (size_t)k * DD);
        double s = 0.0;
        for (int i = 0; i < DD / 4; ++i) {
            float4 v = row[i];
            s += (double)v.x * v.x + (double)v.y * v.y + (double)v.z * v.z + (double)v.w * v.w;
        }
        wsqs[k] = (float)s;
    }

    const float* Zb = Z + (size_t)b * DD * NT + t0;

    float best[8]; int bidx[8];
    #pragma unroll
    for (int a = 0; a < 8; ++a) { best[a] = INFINITY; bidx[a] = 0x7fffffff; }
    double zsqd[8];
    #pragma unroll
    for (int a = 0; a < 8; ++a) zsqd[a] = 0.0;
    float zsqf[8];

    for (int kc = 0; kc < NKC; ++kc) {
        float acc[8][8];
        #pragma unroll
        for (int a = 0; a < 8; ++a)
            #pragma unroll
            for (int c = 0; c < 8; ++c) acc[a][c] = 0.f;

        for (int dc = 0; dc < NDC; ++dc) {
            const int d0 = dc * DCHUNK;
            __syncthreads();
            #pragma unroll
            for (int i = 0; i < 4; ++i) {
                int f  = tid + i * 256;
                int r  = f >> 5;
                int c4 = f & 31;
                float4 v = *(const float4*)(Zb + (size_t)(d0 + r) * NT + c4 * 4);
                *(float4*)(&Zs[r * BT + c4 * 4]) = v;
            }
            #pragma unroll
            for (int i = 0; i < 4; ++i) {
                int u  = tid + i * 256;
                int k  = u >> 3;
                int rg = u & 7;
                float4 v = *(const float4*)(W + (size_t)(kc * BK + k) * DD + d0 + rg * 4);
                Ws[(rg * 4 + 0) * WSTR + k] = v.x;
                Ws[(rg * 4 + 1) * WSTR + k] = v.y;
                Ws[(rg * 4 + 2) * WSTR + k] = v.z;
                Ws[(rg * 4 + 3) * WSTR + k] = v.w;
            }
            __syncthreads();
            #pragma unroll 4
            for (int d = 0; d < DCHUNK; ++d) {
                float4 z0 = *(const float4*)(&Zs[d * BT + ty * 8]);
                float4 z1 = *(const float4*)(&Zs[d * BT + ty * 8 + 4]);
                float4 w0 = *(const float4*)(&Ws[d * WSTR + tx * 8]);
                float4 w1 = *(const float4*)(&Ws[d * WSTR + tx * 8 + 4]);
                float za[8] = {z0.x, z0.y, z0.z, z0.w, z1.x, z1.y, z1.z, z1.w};
                float wa[8] = {w0.x, w0.y, w0.z, w0.w, w1.x, w1.y, w1.z, w1.w};
                if (kc == 0) {
                    #pragma unroll
                    for (int a = 0; a < 8; ++a)
                        zsqd[a] = fma((double)za[a], (double)za[a], zsqd[a]);
                }
                #pragma unroll
                for (int a = 0; a < 8; ++a)
                    #pragma unroll
                    for (int c = 0; c < 8; ++c)
                        acc[a][c] = fmaf(za[a], wa[c], acc[a][c]);
            }
        }
        if (kc == 0) {
            #pragma unroll
            for (int a = 0; a < 8; ++a) zsqf[a] = (float)zsqd[a];
        }
        #pragma unroll
        for (int c = 0; c < 8; ++c) {
            int   kg = kc * BK + tx * 8 + c;
            float wqv = wsqs[kg];
            #pragma unroll
            for (int a = 0; a < 8; ++a) {
                float c2   = __fmul_rn(2.0f, acc[a][c]);
                float s    = __fsub_rn(zsqf[a], c2);
                float dist = __fadd_rn(s, wqv);
                if (dist < best[a] || (dist == best[a] && kg < bidx[a])) {
                    best[a] = dist; bidx[a] = kg;
                }
            }
        }
    }
    __syncthreads();
    float* redv = Zs;
    int*   redi = (int*)Ws;
    #pragma unroll
    for (int a = 0; a < 8; ++a) {
        int tl2 = ty * 8 + a;
        redv[tl2 * 16 + tx] = best[a];
        redi[tl2 * 16 + tx] = bidx[a];
    }
    __syncthreads();
    if (tid < BT) {
        float bv = INFINITY; int bi = 0x7fffffff;
        #pragma unroll
        for (int j = 0; j < 16; ++j) {
            float v = redv[tid * 16 + j];
            int   i = redi[tid * 16 + j];
            if (v < bv || (v == bv && i < bi)) { bv = v; bi = i; }
        }
        out[(size_t)b * NT + t0 + tid] = bi;
    }
}

extern "C" void kernel_launch(void* const* d_in, const int* in_sizes, int n_in,
                              void* d_out, int out_size, void* d_ws, size_t ws_size,
                              hipStream_t stream) {
    const float* Z = (const float*)d_in[0];   // [B, D, T]
    const float* W = (const float*)d_in[1];   // [K, D]
    int* out = (int*)d_out;                   // [B, T]

    // ws layout
    const size_t OFF_WSQ  = 0;                       // 512 f32
    const size_t OFF_CNT  = 2048;                    // 1 int
    const size_t OFF_LIST = 4096;                    // 131072 int
    const size_t OFF_WPP  = OFF_LIST + 524288;       // 512 KB
    const size_t OFF_GQ1  = OFF_WPP + 524288;
    const size_t OFF_GQ2  = OFF_GQ1 + 1048576;
    const size_t OFF_GI1  = OFF_GQ2 + 1048576;
    const size_t NEED     = OFF_GI1 + 1048576;       // ~4.2 MB

    if (ws_size >= NEED) {
        float* wsq = (float*)((char*)d_ws + OFF_WSQ);
        int*   cnt = (int*)((char*)d_ws + OFF_CNT);
        int*   list = (int*)((char*)d_ws + OFF_LIST);
        unsigned short* wpp = (unsigned short*)((char*)d_ws + OFF_WPP);
        float* gq1 = (float*)((char*)d_ws + OFF_GQ1);
        float* gq2 = (float*)((char*)d_ws + OFF_GQ2);
        int*   gi1 = (int*)((char*)d_ws + OFF_GI1);

        prep_kernel<<<dim3(NCH + 1), dim3(512), 0, stream>>>(W, wpp, wsq, cnt);
        vq_phase1<<<dim3(2048), dim3(256), 0, stream>>>(Z, wpp, wsq, gq1, gq2, gi1);
        vq_merge<<<dim3(512), dim3(256), 0, stream>>>(gq1, gq2, gi1, out, list, cnt);
        vq_fix<<<dim3(512), dim3(256), 0, stream>>>(Z, W, wsq, list, cnt, out);
    } else {
        vq_fallback<<<dim3(NT / BT, NB), dim3(256), 0, stream>>>(Z, W, out);
    }
}